// Round 5
// baseline (153.759 us; speedup 1.0000x reference)
//
#include <hip/hip_runtime.h>

// VQ-VAE vector quantizer: B=32,C=64,H=64,W=64, K=512, DECAY=0.99, EPS=1e-5
// N = 131072 vectors, dim 64.
// R5: occupancy attack. vq_argmin: 1024 thr, 4 waves/SIMD (VGPR<=128), codebook
// in LDS (split hi/lo, 16B-stride conflict-free), MFMA 32x32x16 4-term hi/lo,
// top-2 + exact-fp32 refine (proven numerics). out written as q (==x+(q-x) to 1ulp,
// no x read). Segment sums c-plane-transposed: 512-float LDS accumulators, loss fused.

typedef __attribute__((ext_vector_type(8))) short bf16x8;
typedef __attribute__((ext_vector_type(16))) float f32x16;

#define MFMA32 __builtin_amdgcn_mfma_f32_32x32x16_bf16

__device__ __forceinline__ unsigned short f2bf(float f) {
    unsigned u = __float_as_uint(f);
    return (unsigned short)((u + 0x7fffu + ((u >> 16) & 1u)) >> 16);
}
__device__ __forceinline__ float bf2f(unsigned short h) {
    return __uint_as_float(((unsigned)h) << 16);
}

// ---- prep: esq + split hi/lo fragment-major bf16 codebook ----
// unit u = cs*2+hh (cs=c/16, hh selects 8-elem half), c = (u>>1)*16 + (u&1)*8 + j
// cbF layout: [hi: (u*512+k)*16B for 64KB][lo: same, +64KB]
__global__ void __launch_bounds__(512)
vq_prep(const float* __restrict__ cb, float* __restrict__ esq, char* __restrict__ cbF) {
    __shared__ float tile[64 * 65];
    const int tid = threadIdx.x;
    const int k0  = blockIdx.x * 64;
    #pragma unroll
    for (int i = tid; i < 4096; i += 512)
        tile[(i >> 6) * 65 + (i & 63)] = cb[k0 * 64 + i];   // coalesced
    __syncthreads();
    const int u  = tid >> 6;            // 0..7
    const int kl = tid & 63;
    const float* row = tile + kl * 65;
    const int cbase = (u >> 1) * 16 + (u & 1) * 8;
    bf16x8 h8, l8;
    #pragma unroll
    for (int j = 0; j < 8; ++j) {
        float e = row[cbase + j];
        unsigned short hb = f2bf(e);
        float lo = e - bf2f(hb);
        h8[j] = (short)hb;
        l8[j] = (short)f2bf(lo);
    }
    const size_t idx = (size_t)(u * 512 + k0 + kl) * 16;
    *(bf16x8*)(cbF + idx)         = h8;
    *(bf16x8*)(cbF + 65536 + idx) = l8;
    if (u == 0) {
        float s = 0.f;
        #pragma unroll
        for (int c = 0; c < 64; ++c) { float v = row[c]; s = fmaf(v, v, s); }
        esq[k0 + kl] = s;
    }
}

// top-2 update; kq ascending -> strict < keeps first (numpy argmin semantics)
__device__ __forceinline__ void upd(float s, int kq, float& b1, int& q1, float& b2, int& q2) {
    bool t1 = s < b1;
    bool t2 = s < b2;
    float nb2 = t1 ? b1 : (t2 ? s : b2);
    int   nq2 = t1 ? q1 : (t2 ? kq : q2);
    b2 = nb2; q2 = nq2;
    b1 = t1 ? s : b1;
    q1 = t1 ? kq : q1;
}

// LDS: cbhi 16384 fl | cblo 16384 fl | esq 512 fl = 133,120 B
#define ARGMIN_LDS_FLOATS 33280

__global__ void __launch_bounds__(1024, 4)
vq_argmin(const float* __restrict__ x, const char* __restrict__ cbF,
          const float* __restrict__ esqg, unsigned int* __restrict__ bkp) {
    extern __shared__ float lds[];
    float* cbhi = lds;
    float* cblo = lds + 16384;
    float* esq  = lds + 32768;
    const int tid  = threadIdx.x;
    const int lane = tid & 63;
    const int wv   = tid >> 6;        // 0..15
    const int l31  = lane & 31;
    const int hh   = lane >> 5;

    // ---- stage codebook fragments (hi||lo, straight copy) + esq ----
    {
        const float4* src = (const float4*)cbF;
        float4* dst = (float4*)lds;
        #pragma unroll
        for (int i = tid; i < 8192; i += 1024) dst[i] = src[i];
        if (tid < 512) esq[tid] = esqg[tid];
    }

    // ---- this wave's 32 x's: B fragments (-2x, hi/lo) ----
    const int n  = (blockIdx.x * 16 + wv) * 32 + l31;
    const int bb = n >> 12, h = (n >> 6) & 63;
    const long gx = (long)bb * 262144 + (long)h * 64 + (n & 63);
    bf16x8 Bh[4], Bl[4];
    #pragma unroll
    for (int cs = 0; cs < 4; ++cs) {
        bf16x8 h8, l8;
        #pragma unroll
        for (int j = 0; j < 8; ++j) {
            float v  = x[gx + (long)(cs * 16 + hh * 8 + j) * 4096];
            float m2 = -2.f * v;
            unsigned short hb = f2bf(m2);
            float lo = m2 - bf2f(hb);
            h8[j] = (short)hb;
            l8[j] = (short)f2bf(lo);
        }
        Bh[cs] = h8; Bl[cs] = l8;
    }
    __syncthreads();

    // ---- K loop: 16 tiles x 32 codes; A from LDS (16B stride: conflict-free) ----
    float b1 = 3.4e38f, b2 = 3.4e38f;
    int   q1 = 0,        q2 = 0;
    const bf16x8* chi = (const bf16x8*)cbhi;
    const bf16x8* clo = (const bf16x8*)cblo;
    #pragma unroll 1
    for (int kt = 0; kt < 16; ++kt) {
        bf16x8 Ah[4], Al[4];
        #pragma unroll
        for (int cs = 0; cs < 4; ++cs) {
            const int fi = (cs * 2 + hh) * 512 + kt * 32 + l31;
            Ah[cs] = chi[fi];
            Al[cs] = clo[fi];
        }
        f32x16 acc = {};
        #pragma unroll
        for (int cs = 0; cs < 4; ++cs) {
            acc = MFMA32(Ah[cs], Bh[cs], acc, 0, 0, 0);
            acc = MFMA32(Al[cs], Bh[cs], acc, 0, 0, 0);
            acc = MFMA32(Ah[cs], Bl[cs], acc, 0, 0, 0);
            acc = MFMA32(Al[cs], Bl[cs], acc, 0, 0, 0);
        }
        #pragma unroll
        for (int g = 0; g < 4; ++g) {
            float4 e4 = *(const float4*)(esq + kt * 32 + 8 * g + 4 * hh);
            const float ev[4] = {e4.x, e4.y, e4.z, e4.w};
            #pragma unroll
            for (int r = 0; r < 4; ++r) {
                int kq = kt * 32 + 8 * g + r;          // hh-free (add 4*hh at merge)
                upd(ev[r] + acc[4 * g + r], kq, b1, q1, b2, q2);
            }
        }
    }

    // ---- merge hh halves (true k = kq + 4*hh), export top-2 packed ----
    {
        float mb1 = b1, mb2 = b2;
        int   mk1 = q1 + 4 * hh, mk2 = q2 + 4 * hh;
        float ob1 = __shfl_xor(mb1, 32, 64); int ok1 = __shfl_xor(mk1, 32, 64);
        float ob2 = __shfl_xor(mb2, 32, 64); int ok2 = __shfl_xor(mk2, 32, 64);
        bool t = (ob1 < mb1) || (ob1 == mb1 && ok1 < mk1);
        float w1 = t ? ob1 : mb1;  int wk1 = t ? ok1 : mk1;
        float l1 = t ? mb1 : ob1;  int lk1 = t ? mk1 : ok1;
        float w2c = t ? ob2 : mb2; int wk2c = t ? ok2 : mk2;
        bool t2 = (w2c < l1) || (w2c == l1 && wk2c < lk1);
        float w2 = t2 ? w2c : l1;  int wk2 = t2 ? wk2c : lk1;
        if (hh == 0) {
            unsigned k2s = (w2 - w1 < 1e-3f) ? (unsigned)wk2 : (unsigned)wk1;
            bkp[n] = (unsigned)wk1 | (k2s << 16);
        }
    }
}

// ---- refine near-ties + write out (= q, == x+(q-x) to 1 ulp) + final index ----
__global__ void __launch_bounds__(256)
vq_out(const float* __restrict__ x, const float* __restrict__ cbg,
       const float* __restrict__ esqg, const unsigned int* __restrict__ bkp,
       unsigned short* __restrict__ bkg, float* __restrict__ out) {
    const int n  = blockIdx.x * 256 + threadIdx.x;
    const int bb = n >> 12, h = (n >> 6) & 63;
    const long gx = (long)bb * 262144 + (long)h * 64 + (n & 63);
    unsigned pk = bkp[n];
    int k1 = (int)(pk & 0xffffu), k2 = (int)(pk >> 16);
    if (k2 != k1) {   // exact fp32 re-decision (R2-proven ordering); rare path
        const float4* e1 = (const float4*)(cbg + (k1 << 6));
        const float4* e2 = (const float4*)(cbg + (k2 << 6));
        float a0 = 0.f, a1 = 0.f, c0 = 0.f, c1 = 0.f;
        #pragma unroll 4
        for (int j = 0; j < 16; ++j) {
            float4 ea = e1[j], eb = e2[j];
            float x0 = x[gx + (long)(4 * j + 0) * 4096];
            float x1 = x[gx + (long)(4 * j + 1) * 4096];
            float x2 = x[gx + (long)(4 * j + 2) * 4096];
            float x3 = x[gx + (long)(4 * j + 3) * 4096];
            a0 = fmaf(x0, ea.x, a0); a1 = fmaf(x1, ea.y, a1);
            a0 = fmaf(x2, ea.z, a0); a1 = fmaf(x3, ea.w, a1);
            c0 = fmaf(x0, eb.x, c0); c1 = fmaf(x1, eb.y, c1);
            c0 = fmaf(x2, eb.z, c0); c1 = fmaf(x3, eb.w, c1);
        }
        float s1 = esqg[k1] - 2.f * (a0 + a1);
        float s2 = esqg[k2] - 2.f * (c0 + c1);
        if (s2 < s1 || (s2 == s1 && k2 < k1)) k1 = k2;
    }
    bkg[n] = (unsigned short)k1;
    const float4* q4 = (const float4*)(cbg + (k1 << 6));
    #pragma unroll
    for (int j = 0; j < 16; ++j) {
        float4 q = q4[j];
        out[gx + (long)(4 * j + 0) * 4096] = q.x;
        out[gx + (long)(4 * j + 1) * 4096] = q.y;
        out[gx + (long)(4 * j + 2) * 4096] = q.z;
        out[gx + (long)(4 * j + 3) * 4096] = q.w;
    }
}

// ---- c-plane segment sums + counts + loss ----
// grid: 256 blocks = (c 0..63) x (quarter 0..3); 1024 threads
__global__ void __launch_bounds__(1024)
vq_segsum(const float* __restrict__ x, const float* __restrict__ cbg,
          const unsigned short* __restrict__ bkg, float* __restrict__ psum,
          float* __restrict__ hsum, float* __restrict__ acc_loss) {
    __shared__ float ldss[512];
    __shared__ float ldsq[512];
    __shared__ float ldsh[512];
    __shared__ float lred[16];
    const int c  = blockIdx.x >> 2;
    const int qq = blockIdx.x & 3;
    const int tid = threadIdx.x;
    if (tid < 512) {
        ldss[tid] = 0.f;
        ldsh[tid] = 0.f;
        ldsq[tid] = cbg[tid * 64 + c];   // q-table for this plane (L2-hot, once)
    }
    __syncthreads();
    const int nbase = qq * 32768;
    float lsum = 0.f;
    #pragma unroll 4
    for (int i = 0; i < 32; ++i) {
        const int n = nbase + i * 1024 + tid;
        const int k = bkg[n];
        const long g = (long)(n >> 12) * 262144 + (long)c * 4096 + (n & 4095);
        float xv = x[g];
        float d  = xv - ldsq[k];
        lsum = fmaf(d, d, lsum);
        atomicAdd(&ldss[k], xv);
        if (c == 0) atomicAdd(&ldsh[k], 1.0f);
    }
    #pragma unroll
    for (int o = 32; o > 0; o >>= 1) lsum += __shfl_down(lsum, o, 64);
    if ((tid & 63) == 0) lred[tid >> 6] = lsum;
    __syncthreads();
    if (tid < 512) psum[qq * 32768 + tid * 64 + c] = ldss[tid];
    if (c == 0 && tid < 512) hsum[qq * 512 + tid] = ldsh[tid];
    if (tid == 0) {
        float l = 0.f;
        #pragma unroll
        for (int i = 0; i < 16; ++i) l += lred[i];
        atomicAdd(acc_loss, l);
    }
}

__global__ void __launch_bounds__(512)
vq_scalars(const float* __restrict__ hsum, const float* __restrict__ acc_loss,
           const float* __restrict__ ema_cs, float* __restrict__ smoothed,
           float* __restrict__ out_scalars) {
    __shared__ float s_red[17];
    const int tid = threadIdx.x;          // tid == code k
    float cnt = ((hsum[tid] + hsum[512 + tid]) + (hsum[1024 + tid] + hsum[1536 + tid]));
    float ncs = 0.99f * ema_cs[tid] + 0.01f * cnt;
    float v1 = ncs;
    float v2 = (cnt > 0.f) ? 1.f : 0.f;
    #pragma unroll
    for (int o = 32; o > 0; o >>= 1) {
        v1 += __shfl_down(v1, o, 64);
        v2 += __shfl_down(v2, o, 64);
    }
    const int wv = tid >> 6;
    if ((tid & 63) == 0) { s_red[wv] = v1; s_red[wv + 8] = v2; }
    __syncthreads();
    if (tid == 0) {
        float nn = 0.f, uq = 0.f;
        #pragma unroll
        for (int i = 0; i < 8; ++i) { nn += s_red[i]; uq += s_red[i + 8]; }
        s_red[16] = nn;
        out_scalars[0] = acc_loss[0] / 8388608.f;
        out_scalars[1] = uq;
    }
    __syncthreads();
    float nn = s_red[16];
    smoothed[tid] = (ncs + 1e-5f) / (nn + 512.f * 1e-5f) * nn;
}

__global__ void __launch_bounds__(128)
vq_codebook(const float* __restrict__ psum, const float* __restrict__ ema_w,
            const float* __restrict__ smoothed, float* __restrict__ out_cb) {
    const int e = blockIdx.x * 128 + threadIdx.x;      // 0..32767
    float s = (psum[e] + psum[32768 + e]) + (psum[65536 + e] + psum[98304 + e]);
    float nw = 0.99f * ema_w[e] + 0.01f * s;
    out_cb[e] = nw / smoothed[e >> 6];
}

extern "C" void kernel_launch(void* const* d_in, const int* in_sizes, int n_in,
                              void* d_out, int out_size, void* d_ws, size_t ws_size,
                              hipStream_t stream) {
    const float* x      = (const float*)d_in[0];
    const float* cb     = (const float*)d_in[1];
    const float* ema_cs = (const float*)d_in[2];
    const float* ema_w  = (const float*)d_in[3];

    float* out     = (float*)d_out;
    float* scalars = out + 8388608;
    float* out_cb  = out + 8388610;
    float* ws      = (float*)d_ws;

    // ws layout (floats):
    float* psum     = ws;                       // 4*32768 = 131072
    float* hsum     = psum + 131072;            // 4*512  = 2048
    float* smoothed = hsum + 2048;              // 512
    float* esq      = smoothed + 512;           // 512
    float* acc_loss = esq + 512;                // 16
    char*  cbF      = (char*)(acc_loss + 16);   // 131072 B
    unsigned int*   bkp = (unsigned int*)(cbF + 131072);    // 131072 u32
    unsigned short* bkg = (unsigned short*)(bkp + 131072);  // 131072 u16
    // total ~1.3 MB

    hipMemsetAsync(acc_loss, 0, sizeof(float), stream);
    vq_prep<<<8, 512, 0, stream>>>(cb, esq, cbF);
    vq_argmin<<<256, 1024, ARGMIN_LDS_FLOATS * sizeof(float), stream>>>(x, cbF, esq, bkp);
    vq_out<<<512, 256, 0, stream>>>(x, cb, esq, bkp, bkg, out);
    vq_segsum<<<256, 1024, 0, stream>>>(x, cb, bkg, psum, hsum, acc_loss);
    vq_scalars<<<1, 512, 0, stream>>>(hsum, acc_loss, ema_cs, smoothed, scalars);
    vq_codebook<<<256, 128, 0, stream>>>(psum, ema_w, smoothed, out_cb);
}

// Round 6
// 118.556 us; speedup vs baseline: 1.2969x; 1.2969x over previous
//
#include <hip/hip_runtime.h>

// VQ-VAE vector quantizer: B=32,C=64,H=64,W=64, K=512, DECAY=0.99, EPS=1e-5
// N = 131072 vectors, dim 64.
// R6: segsum rebuilt with lane-private replicated LDS accumulator acc[512][32]
// (bank = lane&31 always -> zero bank conflicts, hot-code-proof). Loss+counts
// fused into vq_out. Argmin: drop Al*Bl MFMA term (<=3e-4), refine gate 2e-3.

typedef __attribute__((ext_vector_type(8))) short bf16x8;
typedef __attribute__((ext_vector_type(16))) float f32x16;

#define MFMA32 __builtin_amdgcn_mfma_f32_32x32x16_bf16

__device__ __forceinline__ unsigned short f2bf(float f) {
    unsigned u = __float_as_uint(f);
    return (unsigned short)((u + 0x7fffu + ((u >> 16) & 1u)) >> 16);
}
__device__ __forceinline__ float bf2f(unsigned short h) {
    return __uint_as_float(((unsigned)h) << 16);
}

// ---- prep: esq + split hi/lo fragment-major bf16 codebook ----
// unit u = cs*2+hh, c = (u>>1)*16 + (u&1)*8 + j
// cbF layout: [hi: (u*512+k)*16B for 64KB][lo: same, +64KB]
__global__ void __launch_bounds__(512)
vq_prep(const float* __restrict__ cb, float* __restrict__ esq, char* __restrict__ cbF) {
    __shared__ float tile[64 * 65];
    const int tid = threadIdx.x;
    const int k0  = blockIdx.x * 64;
    #pragma unroll
    for (int i = tid; i < 4096; i += 512)
        tile[(i >> 6) * 65 + (i & 63)] = cb[k0 * 64 + i];   // coalesced
    __syncthreads();
    const int u  = tid >> 6;            // 0..7
    const int kl = tid & 63;
    const float* row = tile + kl * 65;
    const int cbase = (u >> 1) * 16 + (u & 1) * 8;
    bf16x8 h8, l8;
    #pragma unroll
    for (int j = 0; j < 8; ++j) {
        float e = row[cbase + j];
        unsigned short hb = f2bf(e);
        float lo = e - bf2f(hb);
        h8[j] = (short)hb;
        l8[j] = (short)f2bf(lo);
    }
    const size_t idx = (size_t)(u * 512 + k0 + kl) * 16;
    *(bf16x8*)(cbF + idx)         = h8;
    *(bf16x8*)(cbF + 65536 + idx) = l8;
    if (u == 0) {
        float s = 0.f;
        #pragma unroll
        for (int c = 0; c < 64; ++c) { float v = row[c]; s = fmaf(v, v, s); }
        esq[k0 + kl] = s;
    }
}

// top-2 update; kq ascending -> strict < keeps first (numpy argmin semantics)
__device__ __forceinline__ void upd(float s, int kq, float& b1, int& q1, float& b2, int& q2) {
    bool t1 = s < b1;
    bool t2 = s < b2;
    float nb2 = t1 ? b1 : (t2 ? s : b2);
    int   nq2 = t1 ? q1 : (t2 ? kq : q2);
    b2 = nb2; q2 = nq2;
    b1 = t1 ? s : b1;
    q1 = t1 ? kq : q1;
}

// LDS: cbhi 16384 fl | cblo 16384 fl | esq 512 fl = 133,120 B
#define ARGMIN_LDS_FLOATS 33280

__global__ void __launch_bounds__(1024, 4)
vq_argmin(const float* __restrict__ x, const char* __restrict__ cbF,
          const float* __restrict__ esqg, unsigned int* __restrict__ bkp) {
    extern __shared__ float lds[];
    float* cbhi = lds;
    float* cblo = lds + 16384;
    float* esq  = lds + 32768;
    const int tid  = threadIdx.x;
    const int lane = tid & 63;
    const int wv   = tid >> 6;        // 0..15
    const int l31  = lane & 31;
    const int hh   = lane >> 5;

    // ---- stage codebook fragments (hi||lo) + esq ----
    {
        const float4* src = (const float4*)cbF;
        float4* dst = (float4*)lds;
        #pragma unroll
        for (int i = tid; i < 8192; i += 1024) dst[i] = src[i];
        if (tid < 512) esq[tid] = esqg[tid];
    }

    // ---- this wave's 32 x's: B fragments (-2x, hi/lo) ----
    const int n  = (blockIdx.x * 16 + wv) * 32 + l31;
    const int bb = n >> 12, h = (n >> 6) & 63;
    const long gx = (long)bb * 262144 + (long)h * 64 + (n & 63);
    bf16x8 Bh[4], Bl[4];
    #pragma unroll
    for (int cs = 0; cs < 4; ++cs) {
        bf16x8 h8, l8;
        #pragma unroll
        for (int j = 0; j < 8; ++j) {
            float v  = x[gx + (long)(cs * 16 + hh * 8 + j) * 4096];
            float m2 = -2.f * v;
            unsigned short hb = f2bf(m2);
            float lo = m2 - bf2f(hb);
            h8[j] = (short)hb;
            l8[j] = (short)f2bf(lo);
        }
        Bh[cs] = h8; Bl[cs] = l8;
    }
    __syncthreads();

    // ---- K loop: 16 tiles x 32 codes; A from LDS; 3-term hi/lo (drop Al*Bl) ----
    float b1 = 3.4e38f, b2 = 3.4e38f;
    int   q1 = 0,        q2 = 0;
    const bf16x8* chi = (const bf16x8*)cbhi;
    const bf16x8* clo = (const bf16x8*)cblo;
    #pragma unroll 1
    for (int kt = 0; kt < 16; ++kt) {
        bf16x8 Ah[4], Al[4];
        #pragma unroll
        for (int cs = 0; cs < 4; ++cs) {
            const int fi = (cs * 2 + hh) * 512 + kt * 32 + l31;
            Ah[cs] = chi[fi];
            Al[cs] = clo[fi];
        }
        f32x16 acc = {};
        #pragma unroll
        for (int cs = 0; cs < 4; ++cs) {
            acc = MFMA32(Ah[cs], Bh[cs], acc, 0, 0, 0);
            acc = MFMA32(Al[cs], Bh[cs], acc, 0, 0, 0);
            acc = MFMA32(Ah[cs], Bl[cs], acc, 0, 0, 0);
        }
        #pragma unroll
        for (int g = 0; g < 4; ++g) {
            float4 e4 = *(const float4*)(esq + kt * 32 + 8 * g + 4 * hh);
            const float ev[4] = {e4.x, e4.y, e4.z, e4.w};
            #pragma unroll
            for (int r = 0; r < 4; ++r) {
                int kq = kt * 32 + 8 * g + r;          // hh-free (add 4*hh at merge)
                upd(ev[r] + acc[4 * g + r], kq, b1, q1, b2, q2);
            }
        }
    }

    // ---- merge hh halves (true k = kq + 4*hh), export top-2 packed ----
    {
        float mb1 = b1, mb2 = b2;
        int   mk1 = q1 + 4 * hh, mk2 = q2 + 4 * hh;
        float ob1 = __shfl_xor(mb1, 32, 64); int ok1 = __shfl_xor(mk1, 32, 64);
        float ob2 = __shfl_xor(mb2, 32, 64); int ok2 = __shfl_xor(mk2, 32, 64);
        bool t = (ob1 < mb1) || (ob1 == mb1 && ok1 < mk1);
        float w1 = t ? ob1 : mb1;  int wk1 = t ? ok1 : mk1;
        float l1 = t ? mb1 : ob1;  int lk1 = t ? mk1 : ok1;
        float w2c = t ? ob2 : mb2; int wk2c = t ? ok2 : mk2;
        bool t2 = (w2c < l1) || (w2c == l1 && wk2c < lk1);
        float w2 = t2 ? w2c : l1;  int wk2 = t2 ? wk2c : lk1;
        if (hh == 0) {
            unsigned k2s = (w2 - w1 < 2e-3f) ? (unsigned)wk2 : (unsigned)wk1;
            bkp[n] = (unsigned)wk1 | (k2s << 16);
        }
    }
}

// ---- refine near-ties + out (= q) + loss + counts ----
__global__ void __launch_bounds__(256)
vq_out(const float* __restrict__ x, const float* __restrict__ cbg,
       const float* __restrict__ esqg, const unsigned int* __restrict__ bkp,
       unsigned short* __restrict__ bkg, float* __restrict__ out,
       float* __restrict__ hsum, float* __restrict__ acc_loss) {
    __shared__ float hist[512];
    __shared__ float lred[4];
    const int tid = threadIdx.x;
    hist[tid] = 0.f; hist[tid + 256] = 0.f;
    __syncthreads();
    const int n  = blockIdx.x * 256 + tid;
    const int bb = n >> 12, h = (n >> 6) & 63;
    const long gx = (long)bb * 262144 + (long)h * 64 + (n & 63);
    unsigned pk = bkp[n];
    int k1 = (int)(pk & 0xffffu), k2 = (int)(pk >> 16);
    if (k2 != k1) {   // exact fp32 re-decision (R2-proven ordering); rare path
        const float4* e1 = (const float4*)(cbg + (k1 << 6));
        const float4* e2 = (const float4*)(cbg + (k2 << 6));
        float a0 = 0.f, a1 = 0.f, c0 = 0.f, c1 = 0.f;
        #pragma unroll 4
        for (int j = 0; j < 16; ++j) {
            float4 ea = e1[j], eb = e2[j];
            float x0 = x[gx + (long)(4 * j + 0) * 4096];
            float x1 = x[gx + (long)(4 * j + 1) * 4096];
            float x2 = x[gx + (long)(4 * j + 2) * 4096];
            float x3 = x[gx + (long)(4 * j + 3) * 4096];
            a0 = fmaf(x0, ea.x, a0); a1 = fmaf(x1, ea.y, a1);
            a0 = fmaf(x2, ea.z, a0); a1 = fmaf(x3, ea.w, a1);
            c0 = fmaf(x0, eb.x, c0); c1 = fmaf(x1, eb.y, c1);
            c0 = fmaf(x2, eb.z, c0); c1 = fmaf(x3, eb.w, c1);
        }
        float s1 = esqg[k1] - 2.f * (a0 + a1);
        float s2 = esqg[k2] - 2.f * (c0 + c1);
        if (s2 < s1 || (s2 == s1 && k2 < k1)) k1 = k2;
    }
    bkg[n] = (unsigned short)k1;
    atomicAdd(&hist[k1], 1.0f);
    const float4* q4 = (const float4*)(cbg + (k1 << 6));
    float lsum = 0.f;
    #pragma unroll
    for (int j = 0; j < 16; ++j) {
        float4 q = q4[j];
        const float qv[4] = {q.x, q.y, q.z, q.w};
        #pragma unroll
        for (int r = 0; r < 4; ++r) {
            const int c = 4 * j + r;
            float xc = x[gx + (long)c * 4096];
            out[gx + (long)c * 4096] = qv[r];       // == x+(q-x) to 1 ulp (R5-proven)
            float d = xc - qv[r];
            lsum = fmaf(d, d, lsum);
        }
    }
    #pragma unroll
    for (int o = 32; o > 0; o >>= 1) lsum += __shfl_down(lsum, o, 64);
    if ((tid & 63) == 0) lred[tid >> 6] = lsum;
    __syncthreads();
    if (tid == 0) atomicAdd(acc_loss, (lred[0] + lred[1]) + (lred[2] + lred[3]));
    { float v = hist[tid];       if (v != 0.f) atomicAdd(&hsum[tid], v); }
    { float v = hist[tid + 256]; if (v != 0.f) atomicAdd(&hsum[tid + 256], v); }
}

// ---- c-plane segment sums, lane-private replicated accumulator ----
// grid: 256 blocks = (c 0..63) x (quarter 0..3); 1024 threads; LDS 64 KB
__global__ void __launch_bounds__(1024)
vq_segsum(const float* __restrict__ x, const unsigned short* __restrict__ bkg,
          float* __restrict__ psum) {
    __shared__ float acc[512 * 32];
    const int c   = blockIdx.x >> 2;
    const int qq  = blockIdx.x & 3;
    const int tid = threadIdx.x;
    {
        float4* av = (float4*)acc;
        #pragma unroll
        for (int i = tid; i < 4096; i += 1024) av[i] = float4{0.f, 0.f, 0.f, 0.f};
    }
    __syncthreads();
    const int col   = tid & 31;      // bank = col: always lane-private, conflict-free
    const int nbase = qq * 32768;
    #pragma unroll 4
    for (int i = 0; i < 32; ++i) {
        const int n = nbase + i * 1024 + tid;
        const int k = bkg[n];
        const long g = (long)(n >> 12) * 262144 + (long)c * 4096 + (n & 4095);
        atomicAdd(&acc[k * 32 + col], x[g]);   // 2-way max (lane l vs l+32)
    }
    __syncthreads();
    if (tid < 512) {
        float s = 0.f;
        #pragma unroll
        for (int i = 0; i < 32; ++i) s += acc[tid * 32 + ((i + tid) & 31)];  // rotated: conflict-free
        psum[qq * 32768 + c * 512 + tid] = s;   // [qq][c][k]: coalesced
    }
}

__global__ void __launch_bounds__(512)
vq_scalars(const float* __restrict__ hsum, const float* __restrict__ acc_loss,
           const float* __restrict__ ema_cs, float* __restrict__ smoothed,
           float* __restrict__ out_scalars) {
    __shared__ float s_red[17];
    const int tid = threadIdx.x;          // tid == code k
    float cnt = hsum[tid];
    float ncs = 0.99f * ema_cs[tid] + 0.01f * cnt;
    float v1 = ncs;
    float v2 = (cnt > 0.f) ? 1.f : 0.f;
    #pragma unroll
    for (int o = 32; o > 0; o >>= 1) {
        v1 += __shfl_down(v1, o, 64);
        v2 += __shfl_down(v2, o, 64);
    }
    const int wv = tid >> 6;
    if ((tid & 63) == 0) { s_red[wv] = v1; s_red[wv + 8] = v2; }
    __syncthreads();
    if (tid == 0) {
        float nn = 0.f, uq = 0.f;
        #pragma unroll
        for (int i = 0; i < 8; ++i) { nn += s_red[i]; uq += s_red[i + 8]; }
        s_red[16] = nn;
        out_scalars[0] = acc_loss[0] / 8388608.f;
        out_scalars[1] = uq;
    }
    __syncthreads();
    float nn = s_red[16];
    smoothed[tid] = (ncs + 1e-5f) / (nn + 512.f * 1e-5f) * nn;
}

__global__ void __launch_bounds__(128)
vq_codebook(const float* __restrict__ psum, const float* __restrict__ ema_w,
            const float* __restrict__ smoothed, float* __restrict__ out_cb) {
    const int e = blockIdx.x * 128 + threadIdx.x;      // 0..32767
    const int k = e >> 6, c = e & 63;
    float s = (psum[c * 512 + k] + psum[32768 + c * 512 + k])
            + (psum[65536 + c * 512 + k] + psum[98304 + c * 512 + k]);
    float nw = 0.99f * ema_w[e] + 0.01f * s;
    out_cb[e] = nw / smoothed[k];
}

extern "C" void kernel_launch(void* const* d_in, const int* in_sizes, int n_in,
                              void* d_out, int out_size, void* d_ws, size_t ws_size,
                              hipStream_t stream) {
    const float* x      = (const float*)d_in[0];
    const float* cb     = (const float*)d_in[1];
    const float* ema_cs = (const float*)d_in[2];
    const float* ema_w  = (const float*)d_in[3];

    float* out     = (float*)d_out;
    float* scalars = out + 8388608;
    float* out_cb  = out + 8388610;
    float* ws      = (float*)d_ws;

    // ws layout (floats):
    float* psum     = ws;                       // 4*32768 = 131072
    float* hsum     = psum + 131072;            // 512
    float* acc_loss = hsum + 512;               // 16
    float* smoothed = acc_loss + 16;            // 512
    float* esq      = smoothed + 512;           // 512
    char*  cbF      = (char*)(esq + 512);       // 131072 B
    unsigned int*   bkp = (unsigned int*)(cbF + 131072);    // 131072 u32
    unsigned short* bkg = (unsigned short*)(bkp + 131072);  // 131072 u16
    // total ~1.3 MB

    hipMemsetAsync(hsum, 0, 528 * sizeof(float), stream);   // hsum + acc_loss
    vq_prep<<<8, 512, 0, stream>>>(cb, esq, cbF);
    vq_argmin<<<256, 1024, ARGMIN_LDS_FLOATS * sizeof(float), stream>>>(x, cbF, esq, bkp);
    vq_out<<<512, 256, 0, stream>>>(x, cb, esq, bkp, bkg, out, hsum, acc_loss);
    vq_segsum<<<256, 1024, 0, stream>>>(x, bkg, psum);
    vq_scalars<<<1, 512, 0, stream>>>(hsum, acc_loss, ema_cs, smoothed, scalars);
    vq_codebook<<<256, 128, 0, stream>>>(psum, ema_w, smoothed, out_cb);
}